// Round 14
// baseline (2002.703 us; speedup 1.0000x reference)
//
#include <hip/hip_runtime.h>
#include <math.h>

#define BB 16
#define CC 128
#define LL 16000
#define KK 256
#define SS 3937
#define MM 4000
#define UST 4064          // padded u row stride: 64 front + 3937 + 63 back
#define THRS 0.5f
#define STEP 0.1f         // float32(0.01/0.1) == 0.1f

// ---------------------------------------------------------------------------
// Zero u_pad (pads must read as 0.f; re-poison-safe: run every launch).
// ---------------------------------------------------------------------------
__global__ void k_zero(float4* p, int n4) {
    int i = blockIdx.x * blockDim.x + threadIdx.x;
    int stride = gridDim.x * blockDim.x;
    for (; i < n4; i += stride) p[i] = make_float4(0.f, 0.f, 0.f, 0.f);
}

// ---------------------------------------------------------------------------
// Strided conv1d (K=256, stride=4), fp32 register-tiled implicit GEMM.
// R14 VERBATIM chain (proven ~60us). Single fmaf chain per output, k asc.
// MODE 0: init. MODE 1: LCA update. MODE 2: final -> hardshrink to out.
// PAD=1: u lives in padded ws buffer (stride UST, +64 offset); out=d_out.
// ---------------------------------------------------------------------------
template<int MODE, int PAD>
__global__ __launch_bounds__(256, 2) void k_conv(
    const float* __restrict__ in0,     // x (MODE 0) or recon (MODE 1/2)
    const float* __restrict__ W,       // [C][K] natural
    float* __restrict__ drive,
    float* __restrict__ u,
    float* __restrict__ out)
{
    __shared__ __align__(16) float sW[2][128 * 68];  // 2 x 34.8 KB
    __shared__ __align__(16) float sX[768];
    __shared__ int sFlag;

    const int tid = threadIdx.x;
    const int tx = tid & 15;          // s-minor
    const int ty = tid >> 4;          // c-minor
    const int s0 = blockIdx.x * 128;
    const int b  = blockIdx.y;

    const int sc = tid >> 1;
    const int sg = (tid & 1) * 8;
    const float4* W4 = (const float4*)W;

    if (tid == 0) sFlag = 0;
    __syncthreads();

    bool nz = false;
    #pragma unroll
    for (int h = 0; h < 3; ++h) {
        int t = tid + 256 * h;
        int l = 4 * s0 + t;
        float v = (l < LL) ? in0[b * LL + l] : 0.f;
        sX[t] = v;
        nz |= (v != 0.f);
    }
    if (MODE != 0) { if (nz) atomicOr(&sFlag, 1); }
    __syncthreads();

    float acc[8][8];
    #pragma unroll
    for (int i = 0; i < 8; ++i)
        #pragma unroll
        for (int j = 0; j < 8; ++j) acc[i][j] = 0.f;

    const bool doit = (MODE == 0) || (sFlag != 0);   // block-uniform

    if (doit) {
        {
            float4* dst = (float4*)sW[0];
            #pragma unroll
            for (int w = 0; w < 8; ++w)
                dst[sc * 17 + sg + w] = W4[sc * 64 + sg + w];
        }
        __syncthreads();

        for (int kc = 0; kc < 4; ++kc) {         // k chunks ascending
            float4 pre[8];
            if (kc < 3) {
                #pragma unroll
                for (int w = 0; w < 8; ++w)
                    pre[w] = W4[sc * 64 + (kc + 1) * 16 + sg + w];
            }

            const float* wbuf = sW[kc & 1];
            const int xoff = 64 * kc;

            for (int kk4 = 0; kk4 < 16; ++kk4) {          // k ascending
                float4 xq[8];
                #pragma unroll
                for (int j = 0; j < 8; ++j)
                    xq[j] = *(const float4*)&sX[4 * (tx + 16 * j) + xoff + 4 * kk4];
                float4 w4[8];
                #pragma unroll
                for (int i = 0; i < 8; ++i)
                    w4[i] = *(const float4*)&wbuf[(ty + 16 * i) * 68 + 4 * kk4];
                #pragma unroll
                for (int dk = 0; dk < 4; ++dk) {
                    #pragma unroll
                    for (int i = 0; i < 8; ++i) {
                        float wv = (&w4[i].x)[dk];
                        #pragma unroll
                        for (int j = 0; j < 8; ++j)
                            acc[i][j] = fmaf(wv, (&xq[j].x)[dk], acc[i][j]);
                    }
                }
            }

            if (kc < 3) {
                float4* dst = (float4*)sW[(kc + 1) & 1];
                #pragma unroll
                for (int w = 0; w < 8; ++w)
                    dst[sc * 17 + sg + w] = pre[w];
            }
            __syncthreads();
        }
    }

    // epilogue: locked fp32 elementwise chain; s-contiguous stores
    #pragma unroll
    for (int j = 0; j < 8; ++j) {
        int s = s0 + tx + 16 * j;
        if (s < SS) {
            #pragma unroll
            for (int i = 0; i < 8; ++i) {
                int c = ty + 16 * i;
                size_t idx  = (size_t)(b * CC + c) * SS + s;
                size_t idxu = PAD ? ((size_t)(b * CC + c) * UST + 64 + s) : idx;
                if (MODE == 0) {
                    float d = acc[i][j];
                    drive[idx] = d;
                    u[idxu] = __fmul_rn(STEP, d);   // u1 = 0 + 0.1f*drive
                } else {
                    float uo = u[idxu];
                    float dr = drive[idx];
                    float a  = (fabsf(uo) > THRS) ? uo : 0.f;
                    float t1 = __fsub_rn(dr, uo);
                    float t2 = __fsub_rn(t1, acc[i][j]);
                    float t3 = __fadd_rn(t2, a);
                    float t4 = __fmul_rn(STEP, t3);
                    float un = __fadd_rn(uo, t4);
                    if (MODE == 1) u[idxu] = un;
                    else           out[idx] = (fabsf(un) > THRS) ? un : 0.f;  // final
                }
            }
        }
    }
}

// ---------------------------------------------------------------------------
// Transpose-conv (recon). Chain [bit-path frozen — R29 PROVED it] R5-R30:
//   recon[b][4m+r]: for c = 0..127 asc (4 stages x 32), q = 0..63 asc:
//       acc_r = fmaf(a[b][c][m-63+q], W[c][4*(63-q)+r], acc_r)
// R31 = R30 (r-pair split + fmac_dpp + dbuf staging, 117.7us) + SPLIT-PIPE
// a-fetch: R30 is LDS-instruction-issue bound (256 instr/ch/CU ~ 2050cyc
// of the 2207 measured). Odd q's now read DIRECTLY from padded u on the
// idle VMEM pipe (hbm 2.5%, L1/L2 idle) with on-the-fly hardshrink —
// value- and order-identical to the staged path -> bit-safe. Even q's
// stay in LDS (ds_read2 pairs q,q+2). LDS instr/ch/CU halves to 128.
// u is stored PADDED ([64 | 3937 | 63] stride 4064) so every OOB read
// lands on a zero pad == the staged zero -> NO bounds checks, uniform
// fast path for all blocks (1 block/CU => slowest block gates).
// Fallback (ws too small): R30 verbatim.
// ---------------------------------------------------------------------------
#define FMAC_DPP(ACC, WREG, AREG, QI) \
    asm("v_fmac_f32_dpp %0, %1, %2 row_newbcast:" #QI " row_mask:0xf bank_mask:0xf" \
        : "+v"(ACC) : "v"(WREG), "v"(AREG))

#define QSTEP2(WQ, QB, QI) { \
    float a_ = arow[16 * (QB) + (QI)]; \
    FMAC_DPP(accA, WQ.x, a_, QI); \
    FMAC_DPP(accB, WQ.y, a_, QI); }

#define QSTEP2G(WQ, QB, QI) { \
    float uu_ = grow[16 * (QB) + (QI)]; \
    float a_ = (fabsf(uu_) > THRS) ? uu_ : 0.f; \
    FMAC_DPP(accA, WQ.x, a_, QI); \
    FMAC_DPP(accB, WQ.y, a_, QI); }

#define QBLOCK2(WQ, QB) \
    QSTEP2(WQ, QB, 0)  QSTEP2(WQ, QB, 1)  QSTEP2(WQ, QB, 2)  QSTEP2(WQ, QB, 3)  \
    QSTEP2(WQ, QB, 4)  QSTEP2(WQ, QB, 5)  QSTEP2(WQ, QB, 6)  QSTEP2(WQ, QB, 7)  \
    QSTEP2(WQ, QB, 8)  QSTEP2(WQ, QB, 9)  QSTEP2(WQ, QB, 10) QSTEP2(WQ, QB, 11) \
    QSTEP2(WQ, QB, 12) QSTEP2(WQ, QB, 13) QSTEP2(WQ, QB, 14) QSTEP2(WQ, QB, 15)

#define QBLOCK2S(WQ, QB) \
    QSTEP2(WQ, QB, 0)  QSTEP2G(WQ, QB, 1)  QSTEP2(WQ, QB, 2)  QSTEP2G(WQ, QB, 3)  \
    QSTEP2(WQ, QB, 4)  QSTEP2G(WQ, QB, 5)  QSTEP2(WQ, QB, 6)  QSTEP2G(WQ, QB, 7)  \
    QSTEP2(WQ, QB, 8)  QSTEP2G(WQ, QB, 9)  QSTEP2(WQ, QB, 10) QSTEP2G(WQ, QB, 11) \
    QSTEP2(WQ, QB, 12) QSTEP2G(WQ, QB, 13) QSTEP2(WQ, QB, 14) QSTEP2G(WQ, QB, 15)

// ------------------------- padded split-pipe version ------------------------
__global__ __launch_bounds__(512, 1) void k_recon_sp(
    const float* __restrict__ up,      // padded u
    const float* __restrict__ W,
    float* __restrict__ recon)
{
    __shared__ __align__(16) float sA[2][32 * 320];   // 2 x 40.96 KB
    __shared__ int sFlag;

    const int tid  = threadIdx.x;      // [0,512)
    const int p    = tid & 15;
    const int ml   = tid & 255;
    const int rp   = (tid >> 8) << 1;  // 0 | 2, wave-uniform
    const int m0 = blockIdx.x * 256;
    const int b  = blockIdx.y;
    const int m  = m0 + ml;

    if (tid == 0) sFlag = 0;
    __syncthreads();

    float accA = 0.f, accB = 0.f;

    const float* Wq0 = W + 4 * (63 - p)      + rp;
    const float* Wq1 = W + 4 * (63 - 16 - p) + rp;
    const float* Wq2 = W + 4 * (63 - 32 - p) + rp;
    const float* Wq3 = W + 4 * (63 - 48 - p) + rp;

    // per-lane base into padded u for this thread's window (in-row idx m0+1+ml)
    const float* gub = up + (size_t)b * CC * UST + (m0 + 1) + ml;

    // ---- prologue: stage 0 into buf 0 (bounds-free padded reads) ----
    {
        bool nz = false;
        #pragma unroll
        for (int h = 0; h < 20; ++h) {
            int idx = tid + 512 * h;
            int cl  = idx / 320;
            int col = idx - cl * 320;
            float v = 0.f;
            if (col < 319) {
                float uu = up[(size_t)(b * CC + cl) * UST + (m0 + 1) + col];
                v = (fabsf(uu) > THRS) ? uu : 0.f;
            }
            sA[0][idx] = v;
            nz |= (v != 0.f);
        }
        if (nz) atomicOr(&sFlag, 1);
    }

    for (int cs = 0; cs < 4; ++cs) {
        const int c0 = cs * 32;

        __syncthreads();
        const int f = (sFlag >> cs) & 1;

        // issue next stage's loads early (hide under compute)
        float pv[20];
        if (cs < 3) {
            const int c0n = (cs + 1) * 32;
            #pragma unroll
            for (int h = 0; h < 20; ++h) {
                int idx = tid + 512 * h;
                int cl  = idx / 320;
                int col = idx - cl * 320;
                float v = 0.f;
                if (col < 319)
                    v = up[(size_t)(b * CC + c0n + cl) * UST + (m0 + 1) + col];
                pv[h] = v;
            }
        }

        if (f) {
            const float* buf = sA[cs & 1];
            size_t co = (size_t)c0 * KK;
            float2 w0 = *(const float2*)(Wq0 + co);
            float2 w1 = *(const float2*)(Wq1 + co);
            float2 w2 = *(const float2*)(Wq2 + co);
            float2 w3 = *(const float2*)(Wq3 + co);

            for (int cl = 0; cl < 32; ++cl) {
                float2 n0, n1, n2, n3;
                if (cl < 31) {
                    size_t cn = (size_t)(c0 + cl + 1) * KK;
                    n0 = *(const float2*)(Wq0 + cn);
                    n1 = *(const float2*)(Wq1 + cn);
                    n2 = *(const float2*)(Wq2 + cn);
                    n3 = *(const float2*)(Wq3 + cn);
                }

                const float* arow = buf + cl * 320 + ml;
                const float* grow = gub + (size_t)(c0 + cl) * UST;  // grow[q]
                QBLOCK2S(w0, 0)
                QBLOCK2S(w1, 1)
                QBLOCK2S(w2, 2)
                QBLOCK2S(w3, 3)

                w0 = n0; w1 = n1; w2 = n2; w3 = n3;
            }
        }

        if (cs < 3) {
            bool nz = false;
            float* dst = sA[(cs + 1) & 1];
            #pragma unroll
            for (int h = 0; h < 20; ++h) {
                int idx = tid + 512 * h;
                float uu = pv[h];
                float v = (fabsf(uu) > THRS) ? uu : 0.f;
                dst[idx] = v;
                nz |= (v != 0.f);
            }
            if (nz) atomicOr(&sFlag, 1 << (cs + 1));
        }
    }

    if (m < MM) {
        float2* o = (float2*)(recon + (size_t)b * LL + 4 * m + rp);
        *o = make_float2(accA, accB);
    }
}

// ------------------------- fallback (R30 verbatim) --------------------------
__global__ __launch_bounds__(512, 1) void k_recon_base(
    const float* __restrict__ u,
    const float* __restrict__ W,
    float* __restrict__ recon)
{
    __shared__ __align__(16) float sA[2][32 * 320];
    __shared__ int sFlag;

    const int tid  = threadIdx.x;
    const int p    = tid & 15;
    const int ml   = tid & 255;
    const int rp   = (tid >> 8) << 1;
    const int m0 = blockIdx.x * 256;
    const int b  = blockIdx.y;
    const int m  = m0 + ml;

    if (tid == 0) sFlag = 0;
    __syncthreads();

    float accA = 0.f, accB = 0.f;

    const float* Wq0 = W + 4 * (63 - p)      + rp;
    const float* Wq1 = W + 4 * (63 - 16 - p) + rp;
    const float* Wq2 = W + 4 * (63 - 32 - p) + rp;
    const float* Wq3 = W + 4 * (63 - 48 - p) + rp;

    {
        bool nz = false;
        #pragma unroll
        for (int h = 0; h < 20; ++h) {
            int idx = tid + 512 * h;
            int cl  = idx / 320;
            int col = idx - cl * 320;
            int mm  = m0 - 63 + col;
            float v = 0.f;
            if (col < 319 && mm >= 0 && mm < SS) {
                float uu = u[(size_t)(b * CC + cl) * SS + mm];
                v = (fabsf(uu) > THRS) ? uu : 0.f;
            }
            sA[0][idx] = v;
            nz |= (v != 0.f);
        }
        if (nz) atomicOr(&sFlag, 1);
    }

    for (int cs = 0; cs < 4; ++cs) {
        const int c0 = cs * 32;

        __syncthreads();
        const int f = (sFlag >> cs) & 1;

        float pv[20];
        if (cs < 3) {
            const int c0n = (cs + 1) * 32;
            #pragma unroll
            for (int h = 0; h < 20; ++h) {
                int idx = tid + 512 * h;
                int cl  = idx / 320;
                int col = idx - cl * 320;
                int mm  = m0 - 63 + col;
                float v = 0.f;
                if (col < 319 && mm >= 0 && mm < SS)
                    v = u[(size_t)(b * CC + c0n + cl) * SS + mm];
                pv[h] = v;
            }
        }

        if (f) {
            const float* buf = sA[cs & 1];
            size_t co = (size_t)c0 * KK;
            float2 w0 = *(const float2*)(Wq0 + co);
            float2 w1 = *(const float2*)(Wq1 + co);
            float2 w2 = *(const float2*)(Wq2 + co);
            float2 w3 = *(const float2*)(Wq3 + co);

            for (int cl = 0; cl < 32; ++cl) {
                float2 n0, n1, n2, n3;
                if (cl < 31) {
                    size_t cn = (size_t)(c0 + cl + 1) * KK;
                    n0 = *(const float2*)(Wq0 + cn);
                    n1 = *(const float2*)(Wq1 + cn);
                    n2 = *(const float2*)(Wq2 + cn);
                    n3 = *(const float2*)(Wq3 + cn);
                }

                const float* arow = buf + cl * 320 + ml;
                QBLOCK2(w0, 0)
                QBLOCK2(w1, 1)
                QBLOCK2(w2, 2)
                QBLOCK2(w3, 3)

                w0 = n0; w1 = n1; w2 = n2; w3 = n3;
            }
        }

        if (cs < 3) {
            bool nz = false;
            float* dst = sA[(cs + 1) & 1];
            #pragma unroll
            for (int h = 0; h < 20; ++h) {
                int idx = tid + 512 * h;
                float uu = pv[h];
                float v = (fabsf(uu) > THRS) ? uu : 0.f;
                dst[idx] = v;
                nz |= (v != 0.f);
            }
            if (nz) atomicOr(&sFlag, 1 << (cs + 1));
        }
    }

    if (m < MM) {
        float2* o = (float2*)(recon + (size_t)b * LL + 4 * m + rp);
        *o = make_float2(accA, accB);
    }
}

extern "C" void kernel_launch(void* const* d_in, const int* in_sizes, int n_in,
                              void* d_out, int out_size, void* d_ws, size_t ws_size,
                              hipStream_t stream) {
    const float* x = (const float*)d_in[0];   // [16][1][16000]
    const float* W = (const float*)d_in[1];   // [128][1][256]

    float* ws    = (float*)d_ws;
    float* drive = ws;                                    // 8,062,976 floats
    float* recon = drive + (size_t)BB * CC * SS;          // 256,000 floats
    float* upad  = recon + (size_t)BB * LL;               // 2049*4064 floats

    const size_t upad_f = (size_t)(BB * CC + 1) * UST;    // +1 row slack
    const size_t need = ((size_t)BB * CC * SS + (size_t)BB * LL + upad_f) * 4;

    dim3 gConv(31, 16);   // ceil(3937/128) x B

    if (ws_size >= need) {
        // padded fast path
        k_zero<<<1024, 256, 0, stream>>>((float4*)upad, (int)(upad_f / 4));
        k_conv<0, 1><<<gConv, 256, 0, stream>>>(x, W, drive, upad, (float*)d_out);
        for (int it = 0; it < 9; ++it) {
            k_recon_sp<<<dim3(16, 16), 512, 0, stream>>>(upad, W, recon);
            if (it < 8)
                k_conv<1, 1><<<gConv, 256, 0, stream>>>(recon, W, drive, upad, (float*)d_out);
            else
                k_conv<2, 1><<<gConv, 256, 0, stream>>>(recon, W, drive, upad, (float*)d_out);
        }
    } else {
        // R30 fallback: u lives in d_out
        float* u = (float*)d_out;
        k_conv<0, 0><<<gConv, 256, 0, stream>>>(x, W, drive, u, u);
        for (int it = 0; it < 9; ++it) {
            k_recon_base<<<dim3(16, 16), 512, 0, stream>>>(u, W, recon);
            if (it < 8)
                k_conv<1, 0><<<gConv, 256, 0, stream>>>(recon, W, drive, u, u);
            else
                k_conv<2, 0><<<gConv, 256, 0, stream>>>(recon, W, drive, u, u);
        }
    }
}

// Round 15
// 1706.064 us; speedup vs baseline: 1.1739x; 1.1739x over previous
//
#include <hip/hip_runtime.h>
#include <math.h>

#define BB 16
#define CC 128
#define LL 16000
#define KK 256
#define SS 3937
#define MM 4000
#define THRS 0.5f
#define STEP 0.1f   // float32(0.01/0.1) == 0.1f

// ---------------------------------------------------------------------------
// Strided conv1d (K=256, stride=4), fp32 register-tiled implicit GEMM.
// R14 VERBATIM chain (proven ~60us). Single fmaf chain per output, k asc.
// MODE 0: init. MODE 1: LCA update. MODE 2: final -> hardshrink to d_out.
// ---------------------------------------------------------------------------
template<int MODE>
__global__ __launch_bounds__(256, 2) void k_conv(
    const float* __restrict__ in0,     // x (MODE 0) or recon (MODE 1/2)
    const float* __restrict__ W,       // [C][K] natural
    float* __restrict__ drive,
    float* __restrict__ u)
{
    __shared__ __align__(16) float sW[2][128 * 68];  // 2 x 34.8 KB
    __shared__ __align__(16) float sX[768];
    __shared__ int sFlag;

    const int tid = threadIdx.x;
    const int tx = tid & 15;          // s-minor
    const int ty = tid >> 4;          // c-minor
    const int s0 = blockIdx.x * 128;
    const int b  = blockIdx.y;

    const int sc = tid >> 1;
    const int sg = (tid & 1) * 8;
    const float4* W4 = (const float4*)W;

    if (tid == 0) sFlag = 0;
    __syncthreads();

    bool nz = false;
    #pragma unroll
    for (int h = 0; h < 3; ++h) {
        int t = tid + 256 * h;
        int l = 4 * s0 + t;
        float v = (l < LL) ? in0[b * LL + l] : 0.f;
        sX[t] = v;
        nz |= (v != 0.f);
    }
    if (MODE != 0) { if (nz) atomicOr(&sFlag, 1); }
    __syncthreads();

    float acc[8][8];
    #pragma unroll
    for (int i = 0; i < 8; ++i)
        #pragma unroll
        for (int j = 0; j < 8; ++j) acc[i][j] = 0.f;

    const bool doit = (MODE == 0) || (sFlag != 0);   // block-uniform

    if (doit) {
        {
            float4* dst = (float4*)sW[0];
            #pragma unroll
            for (int w = 0; w < 8; ++w)
                dst[sc * 17 + sg + w] = W4[sc * 64 + sg + w];
        }
        __syncthreads();

        for (int kc = 0; kc < 4; ++kc) {         // k chunks ascending
            float4 pre[8];
            if (kc < 3) {
                #pragma unroll
                for (int w = 0; w < 8; ++w)
                    pre[w] = W4[sc * 64 + (kc + 1) * 16 + sg + w];
            }

            const float* wbuf = sW[kc & 1];
            const int xoff = 64 * kc;

            for (int kk4 = 0; kk4 < 16; ++kk4) {          // k ascending
                float4 xq[8];
                #pragma unroll
                for (int j = 0; j < 8; ++j)
                    xq[j] = *(const float4*)&sX[4 * (tx + 16 * j) + xoff + 4 * kk4];
                float4 w4[8];
                #pragma unroll
                for (int i = 0; i < 8; ++i)
                    w4[i] = *(const float4*)&wbuf[(ty + 16 * i) * 68 + 4 * kk4];
                #pragma unroll
                for (int dk = 0; dk < 4; ++dk) {
                    #pragma unroll
                    for (int i = 0; i < 8; ++i) {
                        float wv = (&w4[i].x)[dk];
                        #pragma unroll
                        for (int j = 0; j < 8; ++j)
                            acc[i][j] = fmaf(wv, (&xq[j].x)[dk], acc[i][j]);
                    }
                }
            }

            if (kc < 3) {
                float4* dst = (float4*)sW[(kc + 1) & 1];
                #pragma unroll
                for (int w = 0; w < 8; ++w)
                    dst[sc * 17 + sg + w] = pre[w];
            }
            __syncthreads();
        }
    }

    // epilogue: locked fp32 elementwise chain; s-contiguous stores
    #pragma unroll
    for (int j = 0; j < 8; ++j) {
        int s = s0 + tx + 16 * j;
        if (s < SS) {
            #pragma unroll
            for (int i = 0; i < 8; ++i) {
                int c = ty + 16 * i;
                size_t idx = (size_t)(b * CC + c) * SS + s;
                if (MODE == 0) {
                    float d = acc[i][j];
                    drive[idx] = d;
                    u[idx] = __fmul_rn(STEP, d);   // u1 = 0 + 0.1f*drive
                } else {
                    float uo = u[idx];
                    float dr = drive[idx];
                    float a  = (fabsf(uo) > THRS) ? uo : 0.f;
                    float t1 = __fsub_rn(dr, uo);
                    float t2 = __fsub_rn(t1, acc[i][j]);
                    float t3 = __fadd_rn(t2, a);
                    float t4 = __fmul_rn(STEP, t3);
                    float un = __fadd_rn(uo, t4);
                    if (MODE == 1) u[idx] = un;
                    else           u[idx] = (fabsf(un) > THRS) ? un : 0.f;  // final
                }
            }
        }
    }
}

// ---------------------------------------------------------------------------
// Transpose-conv (recon). Chain [bit-path frozen — R29 PROVED it: q-half
// regroup flipped a hardshrink boundary, absmax 0.5]:
//   recon[b][4m+r]: for c = 0..127 asc (4 stages x 32), q = 0..63 asc:
//       acc_r = fmaf(a[b][c][m-63+q], W[c][4*(63-q)+r], acc_r)
// R32 = R30 VERBATIM (session best, 117.7us k_recon / 1699.9us total).
// TERMINAL STRUCTURE — why each axis is closed:
//  - r-pair split + 512 thr = 2 waves/SIMD (R26: +38us vs 1-wave).
//  - fmac_dpp row_newbcast w-broadcast: 0 extra ops, clean 4cyc
//    (R27: beats readlane by 16us; readlane carries SGPR hazards).
//  - double-buffered async staging hides the u-fetch (R30: -12us).
//  - LDS pipe = 93% busy (2050/2207 cyc/ch/CU at measured 73-85 B/cyc):
//    the r-split duplicates a-window bytes; that duplication is the
//    price of 2-wave occupancy (4-split doubles it; no-split = 1 wave).
//  - Register shift schemes (load window once, DPP-shift per q) die on
//    the VALU-write->DPP-read hazard (R23's lesson).
//  - Split-pipe VMEM odd-q (R31): +42% — defeats staging reuse
//    (FETCH 22->31MB) and VMEM L1 throughput is worse than LDS.
//  - Sum restructuring (q/c-split, MFMA, pk) forbidden by R29 proof.
//  - k_conv frozen at prior-session floor (43% fp32 peak + epilogue HBM).
// ---------------------------------------------------------------------------
#define FMAC_DPP(ACC, WREG, AREG, QI) \
    asm("v_fmac_f32_dpp %0, %1, %2 row_newbcast:" #QI " row_mask:0xf bank_mask:0xf" \
        : "+v"(ACC) : "v"(WREG), "v"(AREG))

#define QSTEP2(WQ, QB, QI) { \
    float a_ = arow[16 * (QB) + (QI)]; \
    FMAC_DPP(accA, WQ.x, a_, QI); \
    FMAC_DPP(accB, WQ.y, a_, QI); }

#define QBLOCK2(WQ, QB) \
    QSTEP2(WQ, QB, 0)  QSTEP2(WQ, QB, 1)  QSTEP2(WQ, QB, 2)  QSTEP2(WQ, QB, 3)  \
    QSTEP2(WQ, QB, 4)  QSTEP2(WQ, QB, 5)  QSTEP2(WQ, QB, 6)  QSTEP2(WQ, QB, 7)  \
    QSTEP2(WQ, QB, 8)  QSTEP2(WQ, QB, 9)  QSTEP2(WQ, QB, 10) QSTEP2(WQ, QB, 11) \
    QSTEP2(WQ, QB, 12) QSTEP2(WQ, QB, 13) QSTEP2(WQ, QB, 14) QSTEP2(WQ, QB, 15)

__global__ __launch_bounds__(512, 1) void k_recon(
    const float* __restrict__ u,
    const float* __restrict__ W,       // [C][K] natural layout
    float* __restrict__ recon)         // [B][LL]
{
    __shared__ __align__(16) float sA[2][32 * 320];   // 2 x 40.96 KB
    __shared__ int sFlag;

    const int tid  = threadIdx.x;      // [0,512)
    const int p    = tid & 15;         // row position for w layout
    const int ml   = tid & 255;        // m_local
    const int rp   = (tid >> 8) << 1;  // 0 | 2, wave-uniform
    const int m0 = blockIdx.x * 256;
    const int b  = blockIdx.y;
    const int m  = m0 + ml;

    if (tid == 0) sFlag = 0;
    __syncthreads();

    float accA = 0.f, accB = 0.f;      // r = rp, rp+1

    // per-lane w fetch bases: quarter qb, element 4*(63-16qb-p)+rp
    const float* Wq0 = W + 4 * (63 - p)      + rp;
    const float* Wq1 = W + 4 * (63 - 16 - p) + rp;
    const float* Wq2 = W + 4 * (63 - 32 - p) + rp;
    const float* Wq3 = W + 4 * (63 - 48 - p) + rp;

    // ---- prologue: stage 0 into buf 0 (serial) ----
    {
        bool nz = false;
        #pragma unroll
        for (int h = 0; h < 20; ++h) {          // 20*512 = 32*320 elements
            int idx = tid + 512 * h;
            int cl  = idx / 320;
            int col = idx - cl * 320;
            int mm  = m0 - 63 + col;
            float v = 0.f;
            if (col < 319 && mm >= 0 && mm < SS) {
                float uu = u[(size_t)(b * CC + cl) * SS + mm];
                v = (fabsf(uu) > THRS) ? uu : 0.f;
            }
            sA[0][idx] = v;
            nz |= (v != 0.f);
        }
        if (nz) atomicOr(&sFlag, 1);            // bit 0
    }

    for (int cs = 0; cs < 4; ++cs) {            // 32-channel stages, c ascending
        const int c0 = cs * 32;

        __syncthreads();                        // buf[cs&1] staged, bit cs set
        const int f = (sFlag >> cs) & 1;        // others only touch bit cs+1

        // ---- issue next stage's global loads into regs (latency hides
        //      under compute below) ----
        float pv[20];
        if (cs < 3) {
            const int c0n = (cs + 1) * 32;
            #pragma unroll
            for (int h = 0; h < 20; ++h) {
                int idx = tid + 512 * h;
                int cl  = idx / 320;
                int col = idx - cl * 320;
                int mm  = m0 - 63 + col;
                float v = 0.f;
                if (col < 319 && mm >= 0 && mm < SS)
                    v = u[(size_t)(b * CC + c0n + cl) * SS + mm];
                pv[h] = v;
            }
        }

        // ---- compute on buf[cs&1] (R27 verbatim) ----
        if (f) {
            const float* buf = sA[cs & 1];
            // prologue: w quarters for cl=0
            size_t co = (size_t)c0 * KK;
            float2 w0 = *(const float2*)(Wq0 + co);
            float2 w1 = *(const float2*)(Wq1 + co);
            float2 w2 = *(const float2*)(Wq2 + co);
            float2 w3 = *(const float2*)(Wq3 + co);

            for (int cl = 0; cl < 32; ++cl) {   // c ascending
                float2 n0, n1, n2, n3;
                if (cl < 31) {                  // prefetch next channel
                    size_t cn = (size_t)(c0 + cl + 1) * KK;
                    n0 = *(const float2*)(Wq0 + cn);
                    n1 = *(const float2*)(Wq1 + cn);
                    n2 = *(const float2*)(Wq2 + cn);
                    n3 = *(const float2*)(Wq3 + cn);
                }

                const float* arow = buf + cl * 320 + ml;  // arow[q] = a[c][m-63+q]
                QBLOCK2(w0, 0)
                QBLOCK2(w1, 1)
                QBLOCK2(w2, 2)
                QBLOCK2(w3, 3)

                w0 = n0; w1 = n1; w2 = n2; w3 = n3;
            }
        }

        // ---- finish staging stage cs+1 into buf[(cs+1)&1] ----
        if (cs < 3) {
            bool nz = false;
            float* dst = sA[(cs + 1) & 1];
            #pragma unroll
            for (int h = 0; h < 20; ++h) {
                int idx = tid + 512 * h;
                float uu = pv[h];
                float v = (fabsf(uu) > THRS) ? uu : 0.f;
                dst[idx] = v;
                nz |= (v != 0.f);
            }
            if (nz) atomicOr(&sFlag, 1 << (cs + 1));
        }
    }

    if (m < MM) {
        float2* o = (float2*)(recon + (size_t)b * LL + 4 * m + rp);
        *o = make_float2(accA, accB);
    }
}

extern "C" void kernel_launch(void* const* d_in, const int* in_sizes, int n_in,
                              void* d_out, int out_size, void* d_ws, size_t ws_size,
                              hipStream_t stream) {
    const float* x = (const float*)d_in[0];   // [16][1][16000]
    const float* W = (const float*)d_in[1];   // [128][1][256]
    float* u = (float*)d_out;                 // u lives in d_out (fp32)

    float* ws    = (float*)d_ws;              // ~33.3 MB used
    float* drive = ws;                                    // 8062976
    float* recon = drive + (size_t)BB * CC * SS;          // 256000

    dim3 gConv(31, 16);   // ceil(3937/128) x B
    k_conv<0><<<gConv, 256, 0, stream>>>(x, W, drive, u);   // drive + u1

    for (int it = 0; it < 9; ++it) {   // iterations 2..10
        k_recon<<<dim3(16, 16), 512, 0, stream>>>(u, W, recon);
        if (it < 8)
            k_conv<1><<<gConv, 256, 0, stream>>>(recon, W, drive, u);
        else
            k_conv<2><<<gConv, 256, 0, stream>>>(recon, W, drive, u);  // final -> d_out
    }
}